// Round 1
// baseline (746.642 us; speedup 1.0000x reference)
//
#include <hip/hip_runtime.h>
#include <math.h>

// Problem shape (fixed by setup_inputs): [B=16, C=3, T=600, H=72, W=72] fp32.
#define HW_ELEMS 5184            // 72*72
#define HW_VEC   1296            // 5184/4 float4s
#define NT       600
#define NC       3
#define NB       16
#define NSLABS   (NB * NC * NT)  // 28800 (b,c,t) slabs

// ---------------------------------------------------------------------------
// Kernel 1: spatial mean over H*W for each (b,c,t).
// One 256-thread block per slab; slab is contiguous 5184 floats -> coalesced
// float4 loads, wave-64 shuffle reduction, one float out per block.
// Memory-bound: reads 597 MB total.
// ---------------------------------------------------------------------------
__global__ __launch_bounds__(256) void mean_kernel(const float* __restrict__ in,
                                                   float* __restrict__ xbar) {
    const int bi = blockIdx.x;  // flat (b,c,t) index, matches [B,C,T] row-major
    const float4* p = (const float4*)(in + (size_t)bi * HW_ELEMS);

    float s = 0.f;
    for (int i = threadIdx.x; i < HW_VEC; i += 256) {
        float4 v = p[i];
        s += (v.x + v.y) + (v.z + v.w);
    }
    // wave-64 reduction
    #pragma unroll
    for (int off = 32; off > 0; off >>= 1)
        s += __shfl_down(s, off, 64);

    __shared__ float wsum[4];
    const int lane = threadIdx.x & 63;
    const int wid  = threadIdx.x >> 6;
    if (lane == 0) wsum[wid] = s;
    __syncthreads();
    if (threadIdx.x == 0) {
        float t = (wsum[0] + wsum[1]) + (wsum[2] + wsum[3]);
        xbar[bi] = t * (1.0f / (float)HW_ELEMS);
    }
}

// ---------------------------------------------------------------------------
// Kernel 2: per-batch dominant left singular vector + projection.
// G = x x^T (3x3, double accumulation). Top eigenvector via repeated
// squaring with trace normalization: ratio^2 per step -> machine-precision
// convergence in <= 40 steps regardless of eigengap (exact degeneracy aside).
// out[b,t] = x1 - S1 * (S . x_t)
// ---------------------------------------------------------------------------
__global__ __launch_bounds__(256) void project_kernel(const float* __restrict__ xbar,
                                                      float* __restrict__ out) {
    const int b = blockIdx.x;
    __shared__ float  sx[NC][NT];       // 7200 B
    __shared__ double red[6][256];      // 12288 B
    __shared__ float  S[3];

    const float* xb = xbar + b * (NC * NT);
    for (int i = threadIdx.x; i < NC * NT; i += 256)
        ((float*)sx)[i] = xb[i];
    __syncthreads();

    double g0 = 0, g1 = 0, g2 = 0, g3 = 0, g4 = 0, g5 = 0;
    for (int t = threadIdx.x; t < NT; t += 256) {
        double x0 = (double)sx[0][t];
        double x1 = (double)sx[1][t];
        double x2 = (double)sx[2][t];
        g0 += x0 * x0; g1 += x0 * x1; g2 += x0 * x2;
        g3 += x1 * x1; g4 += x1 * x2; g5 += x2 * x2;
    }
    red[0][threadIdx.x] = g0; red[1][threadIdx.x] = g1; red[2][threadIdx.x] = g2;
    red[3][threadIdx.x] = g3; red[4][threadIdx.x] = g4; red[5][threadIdx.x] = g5;
    __syncthreads();
    for (int s = 128; s > 0; s >>= 1) {
        if (threadIdx.x < s) {
            #pragma unroll
            for (int k = 0; k < 6; k++)
                red[k][threadIdx.x] += red[k][threadIdx.x + s];
        }
        __syncthreads();
    }

    if (threadIdx.x == 0) {
        double M[3][3] = {{red[0][0], red[1][0], red[2][0]},
                          {red[1][0], red[3][0], red[4][0]},
                          {red[2][0], red[4][0], red[5][0]}};
        // Repeated squaring with trace normalization: M -> (M/tr(M))^2.
        // Fixed point is v v^T (unit trace); eigen-ratio squares each step.
        for (int it = 0; it < 40; it++) {
            double tr = M[0][0] + M[1][1] + M[2][2];
            double inv = (tr > 0.0) ? (1.0 / tr) : 1.0;
            double T[3][3];
            #pragma unroll
            for (int i = 0; i < 3; i++)
                #pragma unroll
                for (int j = 0; j < 3; j++) T[i][j] = M[i][j] * inv;
            #pragma unroll
            for (int i = 0; i < 3; i++)
                #pragma unroll
                for (int j = 0; j < 3; j++) {
                    double acc = 0.0;
                    #pragma unroll
                    for (int k = 0; k < 3; k++) acc += T[i][k] * T[k][j];
                    M[i][j] = acc;
                }
        }
        // M ~= v v^T; take the column with the largest diagonal (= v_j^2).
        int jm = 0;
        if (M[1][1] > M[jm][jm]) jm = 1;
        if (M[2][2] > M[jm][jm]) jm = 2;
        double v0 = M[0][jm], v1 = M[1][jm], v2 = M[2][jm];
        double nrm = sqrt(v0 * v0 + v1 * v1 + v2 * v2);
        double inv = (nrm > 0.0) ? (1.0 / nrm) : 0.0;
        S[0] = (float)(v0 * inv);
        S[1] = (float)(v1 * inv);
        S[2] = (float)(v2 * inv);
    }
    __syncthreads();

    const float s0 = S[0], s1 = S[1], s2 = S[2];
    for (int t = threadIdx.x; t < NT; t += 256) {
        float x0 = sx[0][t], x1 = sx[1][t], x2 = sx[2][t];
        float d = s0 * x0 + s1 * x1 + s2 * x2;
        out[b * NT + t] = x1 - s1 * d;  // (P x)[1] = x1 - S1 * (S.x)
    }
}

extern "C" void kernel_launch(void* const* d_in, const int* in_sizes, int n_in,
                              void* d_out, int out_size, void* d_ws, size_t ws_size,
                              hipStream_t stream) {
    const float* batch_x = (const float*)d_in[0];
    float* out  = (float*)d_out;           // [B, T] = 9600 floats
    float* xbar = (float*)d_ws;            // [B, C, T] = 28800 floats scratch

    mean_kernel<<<NSLABS, 256, 0, stream>>>(batch_x, xbar);
    project_kernel<<<NB, 256, 0, stream>>>(xbar, out);
}